// Round 9
// baseline (384.077 us; speedup 1.0000x reference)
//
#include <hip/hip_runtime.h>

#define N_TOK 32768
#define N_E   1024
#define E_DIM 64
#define N_BLK 1024
#define RPB2  16
#define SINK_PASSES 4

__device__ __forceinline__ unsigned fkey(float f) {
  unsigned u = __float_as_uint(f);
  return (u & 0x80000000u) ? ~u : (u | 0x80000000u);
}
__device__ __forceinline__ float fdecode(unsigned k) {
  unsigned u = (k & 0x80000000u) ? (k & 0x7FFFFFFFu) : ~k;
  return __uint_as_float(u);
}

__global__ void k0_init(unsigned* minmax, int* usage_i) {
  int t = threadIdx.x;
  if (t == 0) { minmax[0] = 0xFFFFFFFFu; minmax[1] = 0u; }
  for (int i = t; i < N_E; i += 256) usage_i[i] = 0;
}

__global__ void k1_embT(const float* __restrict__ emb, float* __restrict__ embT,
                        float* __restrict__ s_e) {
  int k = blockIdx.x * blockDim.x + threadIdx.x;
  if (k >= N_E) return;
  float s = 0.f;
  for (int j = 0; j < E_DIM; ++j) {
    float v = emb[k * E_DIM + j];
    embT[j * N_E + k] = v;
    s = fmaf(v, v, s);
  }
  s_e[k] = s;
}

// d (f32, bit-identical accumulation order to validated r6/r8) + min/max + ||x||^2.
__global__ __launch_bounds__(256) void k2_dist(const float* __restrict__ x,
    const float* __restrict__ embT, const float* __restrict__ s_e,
    float* __restrict__ dcbuf, unsigned* __restrict__ minmax,
    float* __restrict__ xnorm) {
  __shared__ float xs[RPB2][E_DIM + 4];
  __shared__ float sxl[RPB2];
  __shared__ float smn[4], smx[4];
  const int tid = threadIdx.x;
  const int r0 = blockIdx.x * RPB2;
  for (int i = tid; i < RPB2 * E_DIM; i += 256)
    xs[i >> 6][i & 63] = x[r0 * E_DIM + i];
  __syncthreads();
  if (tid < RPB2) {
    float s = 0.f;
    for (int j = 0; j < E_DIM; ++j) s = fmaf(xs[tid][j], xs[tid][j], s);
    sxl[tid] = s;
    xnorm[r0 + tid] = s;
  }
  __syncthreads();
  const int c0 = tid * 4;
  const float4 se4 = *(const float4*)(s_e + c0);
  const int w = tid >> 6, l = tid & 63;
  float dmn = INFINITY, dmx = -INFINITY;
  for (int rg = 0; rg < 2; ++rg) {
    float acc[4][8];
    #pragma unroll
    for (int a = 0; a < 4; ++a)
      #pragma unroll
      for (int b = 0; b < 8; ++b) acc[a][b] = 0.f;
    for (int j0 = 0; j0 < E_DIM; j0 += 4) {
      float4 eq[4];
      #pragma unroll
      for (int jj = 0; jj < 4; ++jj)
        eq[jj] = *(const float4*)(embT + (size_t)(j0 + jj) * N_E + c0);
      const float* ef = (const float*)eq;
      #pragma unroll
      for (int b = 0; b < 8; ++b) {
        const float4 xv = *(const float4*)(&xs[rg * 8 + b][j0]);
        #pragma unroll
        for (int a = 0; a < 4; ++a) {
          acc[a][b] = fmaf(ef[0 * 4 + a], xv.x, acc[a][b]);
          acc[a][b] = fmaf(ef[1 * 4 + a], xv.y, acc[a][b]);
          acc[a][b] = fmaf(ef[2 * 4 + a], xv.z, acc[a][b]);
          acc[a][b] = fmaf(ef[3 * 4 + a], xv.w, acc[a][b]);
        }
      }
    }
    #pragma unroll
    for (int b = 0; b < 8; ++b) {
      const int row = r0 + rg * 8 + b;
      const float t = sxl[rg * 8 + b];
      float4 dv;
      dv.x = (t + se4.x) - 2.0f * acc[0][b];
      dv.y = (t + se4.y) - 2.0f * acc[1][b];
      dv.z = (t + se4.z) - 2.0f * acc[2][b];
      dv.w = (t + se4.w) - 2.0f * acc[3][b];
      *(float4*)(dcbuf + (size_t)row * N_E + c0) = dv;
      dmn = fminf(dmn, fminf(fminf(dv.x, dv.y), fminf(dv.z, dv.w)));
      dmx = fmaxf(dmx, fmaxf(fmaxf(dv.x, dv.y), fmaxf(dv.z, dv.w)));
    }
  }
  for (int off = 32; off; off >>= 1) {
    dmn = fminf(dmn, __shfl_xor(dmn, off));
    dmx = fmaxf(dmx, __shfl_xor(dmx, off));
  }
  if (l == 0) { smn[w] = dmn; smx[w] = dmx; }
  __syncthreads();
  if (tid == 0) {
    float a = fminf(fminf(smn[0], smn[1]), fminf(smn[2], smn[3]));
    float b = fmaxf(fmaxf(smx[0], smx[1]), fmaxf(smx[2], smx[3]));
    atomicMin(&minmax[0], fkey(a));
    atomicMax(&minmax[1], fkey(b));
  }
}

// Sinkhorn iteration, latency-batched: sweep1 computes per-row partials,
// one pipelined butterfly reduces all 8 rows, sweep2 (reload, dep-free)
// accumulates ua. All FP op sequences bit-identical to the validated r8 kernel.
__global__ __launch_bounds__(256) void k4_pass(const float* __restrict__ dcbuf,
    const float* __restrict__ xnorm, const unsigned* __restrict__ minmax,
    const double* __restrict__ u_in, double* __restrict__ Up, int phase) {
  __shared__ double ulds[4][N_E];
  const float mn = fdecode(minmax[0]);
  const float mx = fdecode(minmax[1]);
  const float middle = (mx + mn) * 0.5f;
  const float amplitude = (mx - middle) + 1e-5f;
  const float s2 = 144.26950408889634f / amplitude;   // 100*log2(e)/amp
  const double escale = -100.0 / (double)amplitude;
  const double mid_d = (double)middle;
  const int tid = threadIdx.x, w = tid >> 6, l = tid & 63;
  const int bid = blockIdx.x;
  const int r0 = bid * 32;
  double ua[16];
  #pragma unroll
  for (int j = 0; j < 16; ++j) ua[j] = 0.0;

  if (phase) {
    double rr[16];
    #pragma unroll
    for (int q = 0; q < 4; ++q)
      #pragma unroll
      for (int m = 0; m < 4; ++m)
        rr[q * 4 + m] = 1.0 / (1024.0 * u_in[4 * l + 256 * q + m]);
    // sweep 1: per-row vs partials (same j-ascending f64 fma order)
    double vsp[8];
    for (int i = 0; i < 8; ++i) {
      const int row = r0 + w + 4 * i;
      const float* dr = dcbuf + (size_t)row * N_E;
      const float m2 = xnorm[row];
      double vs = 0.0;
      #pragma unroll
      for (int q = 0; q < 4; ++q) {
        const float4 v = *(const float4*)(dr + 4 * l + 256 * q);
        const float E0 = exp2f((m2 - v.x) * s2);
        const float E1 = exp2f((m2 - v.y) * s2);
        const float E2 = exp2f((m2 - v.z) * s2);
        const float E3 = exp2f((m2 - v.w) * s2);
        vs = fma((double)E0, rr[q * 4 + 0], vs);
        vs = fma((double)E1, rr[q * 4 + 1], vs);
        vs = fma((double)E2, rr[q * 4 + 2], vs);
        vs = fma((double)E3, rr[q * 4 + 3], vs);
      }
      vsp[i] = vs;
    }
    // batched butterfly: 8 independent chains, same offset order per chain
    for (int off = 32; off; off >>= 1) {
      #pragma unroll
      for (int i = 0; i < 8; ++i) vsp[i] += __shfl_xor(vsp[i], off);
    }
    #pragma unroll
    for (int i = 0; i < 8; ++i) vsp[i] = 1.0 / (32768.0 * vsp[i]);
    // sweep 2: dependency-free ua accumulation (reload is L2/L3-hot)
    for (int i = 0; i < 8; ++i) {
      const int row = r0 + w + 4 * i;
      const float* dr = dcbuf + (size_t)row * N_E;
      const float m2 = xnorm[row];
      const double ch = vsp[i];
      #pragma unroll
      for (int q = 0; q < 4; ++q) {
        const float4 v = *(const float4*)(dr + 4 * l + 256 * q);
        const float E0 = exp2f((m2 - v.x) * s2);
        const float E1 = exp2f((m2 - v.y) * s2);
        const float E2 = exp2f((m2 - v.z) * s2);
        const float E3 = exp2f((m2 - v.w) * s2);
        ua[q * 4 + 0] = fma((double)E0, ch, ua[q * 4 + 0]);
        ua[q * 4 + 1] = fma((double)E1, ch, ua[q * 4 + 1]);
        ua[q * 4 + 2] = fma((double)E2, ch, ua[q * 4 + 2]);
        ua[q * 4 + 3] = fma((double)E3, ch, ua[q * 4 + 3]);
      }
    }
  } else {
    // phase 0: ch analytic per row, single sweep
    for (int i = 0; i < 8; ++i) {
      const int row = r0 + w + 4 * i;
      const float* dr = dcbuf + (size_t)row * N_E;
      const float m2 = xnorm[row];
      const double ch = exp(escale * ((double)m2 - mid_d));
      #pragma unroll
      for (int q = 0; q < 4; ++q) {
        const float4 v = *(const float4*)(dr + 4 * l + 256 * q);
        const float E0 = exp2f((m2 - v.x) * s2);
        const float E1 = exp2f((m2 - v.y) * s2);
        const float E2 = exp2f((m2 - v.z) * s2);
        const float E3 = exp2f((m2 - v.w) * s2);
        ua[q * 4 + 0] = fma((double)E0, ch, ua[q * 4 + 0]);
        ua[q * 4 + 1] = fma((double)E1, ch, ua[q * 4 + 1]);
        ua[q * 4 + 2] = fma((double)E2, ch, ua[q * 4 + 2]);
        ua[q * 4 + 3] = fma((double)E3, ch, ua[q * 4 + 3]);
      }
    }
  }
  #pragma unroll
  for (int q = 0; q < 4; ++q)
    #pragma unroll
    for (int m = 0; m < 4; ++m)
      ulds[w][4 * l + 256 * q + m] = ua[q * 4 + m];
  __syncthreads();
  #pragma unroll
  for (int k = 0; k < 4; ++k) {
    const int c = tid * 4 + k;
    const double s = ulds[0][c] + ulds[1][c] + ulds[2][c] + ulds[3][c];
    Up[(size_t)c * N_BLK + bid] = s;
  }
}

__global__ __launch_bounds__(256) void k4_reduce(const double* __restrict__ Up,
                                                 double* __restrict__ u,
                                                 double* __restrict__ logu, int last) {
  __shared__ double red[4];
  const int c = blockIdx.x;
  const int tid = threadIdx.x, w = tid >> 6, l = tid & 63;
  double s = 0.0;
  for (int i = tid; i < N_BLK; i += 256) s += Up[(size_t)c * N_BLK + i];
  for (int off = 32; off; off >>= 1) s += __shfl_xor(s, off);
  if (l == 0) red[w] = s;
  __syncthreads();
  if (tid == 0) {
    const double t = red[0] + red[1] + red[2] + red[3];
    u[c] = t;
    if (last) logu[c] = -log(t);
  }
}

// argmax + gather, with the 8 per-row argmax butterflies batched.
__global__ __launch_bounds__(256) void k5_out(const float* __restrict__ dcbuf,
    const double* __restrict__ logu, const unsigned* __restrict__ minmax,
    const float* __restrict__ x, const float* __restrict__ emb,
    float* __restrict__ out_xq, float* __restrict__ out_idx,
    int* __restrict__ usage_i, double* __restrict__ lossP) {
  __shared__ double slr[N_E];
  __shared__ double lw[4];
  const float mn = fdecode(minmax[0]);
  const float mx = fdecode(minmax[1]);
  const float middle = (mx + mn) * 0.5f;
  const float amplitude = (mx - middle) + 1e-5f;
  const int tid = threadIdx.x, w = tid >> 6, l = tid & 63;
  const int r0 = blockIdx.x * 32;
  for (int t = tid; t < N_E; t += 256) slr[t] = logu[t];
  __syncthreads();
  double bm[8]; int bci[8];
  for (int i = 0; i < 8; ++i) {
    const int row = r0 + w * 8 + i;
    const float* dr = dcbuf + (size_t)row * N_E;
    double best = -INFINITY; int bc = 0;
    #pragma unroll
    for (int m = 0; m < 16; ++m) {
      const int c = l + 64 * m;
      const float v = (dr[c] - middle) / amplitude;   // reference f32 rounding
      const double s = slr[c] - (double)v * 100.0;
      if (s > best) { best = s; bc = c; }
    }
    bm[i] = best; bci[i] = bc;
  }
  for (int off = 32; off; off >>= 1) {
    #pragma unroll
    for (int i = 0; i < 8; ++i) {
      const double ob = __shfl_xor(bm[i], off);
      const int oc = __shfl_xor(bci[i], off);
      if (ob > bm[i] || (ob == bm[i] && oc < bci[i])) { bm[i] = ob; bci[i] = oc; }
    }
  }
  double lacc = 0.0;
  for (int i = 0; i < 8; ++i) {
    const int row = r0 + w * 8 + i;
    const int bc = bci[i];
    if (l == 0) {
      out_idx[row] = (float)bc;
      atomicAdd(&usage_i[bc], 1);
    }
    const float g = emb[bc * E_DIM + l];
    const float xv = x[(size_t)row * E_DIM + l];
    const float diff = g - xv;
    out_xq[(size_t)row * E_DIM + l] = xv + diff;
    lacc += (double)diff * (double)diff;
  }
  for (int off = 32; off; off >>= 1) lacc += __shfl_xor(lacc, off);
  if (l == 0) lw[w] = lacc;
  __syncthreads();
  if (tid == 0) lossP[blockIdx.x] = lw[0] + lw[1] + lw[2] + lw[3];
}

__global__ void k6_final(const int* __restrict__ usage_in,
    const int* __restrict__ usage_i, const double* __restrict__ lossP,
    float* __restrict__ out_loss, float* __restrict__ out_usage) {
  __shared__ double red[4];
  const int tid = threadIdx.x;
  if (blockIdx.x < 4) {
    const int t = blockIdx.x * 256 + tid;
    out_usage[t] = (float)(usage_in[t] + usage_i[t]);
  } else {
    const int w = tid >> 6, l = tid & 63;
    double s = 0.0;
    for (int i = tid; i < N_BLK; i += 256) s += lossP[i];
    for (int off = 32; off; off >>= 1) s += __shfl_xor(s, off);
    if (l == 0) red[w] = s;
    __syncthreads();
    if (tid == 0)
      out_loss[0] = (float)(2.0 * (red[0] + red[1] + red[2] + red[3]) /
                            (double)((size_t)N_TOK * E_DIM));
  }
}

extern "C" void kernel_launch(void* const* d_in, const int* in_sizes, int n_in,
                              void* d_out, int out_size, void* d_ws, size_t ws_size,
                              hipStream_t stream) {
  const float* x = (const float*)d_in[0];
  const float* emb = (const float*)d_in[1];
  const int* usage_in = (const int*)d_in[4];   // harness: integer inputs are int32
  float* out = (float*)d_out;
  float* out_xq = out;
  float* out_loss = out + (size_t)N_TOK * E_DIM;
  float* out_idx = out_loss + 1;
  float* out_usage = out_idx + N_TOK;

  char* ws = (char*)d_ws;
  size_t off = 0;
  float* dcbuf     = (float*)(ws + off); off += (size_t)N_TOK * N_E * 4;
  float* embT      = (float*)(ws + off); off += (size_t)E_DIM * N_E * 4;
  float* s_e       = (float*)(ws + off); off += N_E * 4;
  float* xnorm     = (float*)(ws + off); off += N_TOK * 4;
  double* ubuf     = (double*)(ws + off); off += N_E * 8;
  double* logu     = (double*)(ws + off); off += N_E * 8;
  double* Up       = (double*)(ws + off); off += (size_t)N_E * N_BLK * 8;
  double* lossP    = (double*)(ws + off); off += N_BLK * 8;
  unsigned* minmax = (unsigned*)(ws + off); off += 8;
  int* usage_i     = (int*)(ws + off); off += N_E * 4;

  hipLaunchKernelGGL(k0_init, dim3(1), dim3(256), 0, stream, minmax, usage_i);
  hipLaunchKernelGGL(k1_embT, dim3(4), dim3(256), 0, stream, emb, embT, s_e);
  hipLaunchKernelGGL(k2_dist, dim3(N_TOK / RPB2), dim3(256), 0, stream, x, embT, s_e,
                     dcbuf, minmax, xnorm);
  for (int p = 0; p < SINK_PASSES; ++p) {
    hipLaunchKernelGGL(k4_pass, dim3(N_BLK), dim3(256), 0, stream, dcbuf, xnorm,
                       minmax, ubuf, Up, p);
    hipLaunchKernelGGL(k4_reduce, dim3(N_E), dim3(256), 0, stream, Up, ubuf, logu,
                       (p == SINK_PASSES - 1) ? 1 : 0);
  }
  hipLaunchKernelGGL(k5_out, dim3(N_BLK), dim3(256), 0, stream, dcbuf, logu, minmax,
                     x, emb, out_xq, out_idx, usage_i, lossP);
  hipLaunchKernelGGL(k6_final, dim3(5), dim3(256), 0, stream, usage_in, usage_i,
                     lossP, out_loss, out_usage);
}

// Round 10
// 294.208 us; speedup vs baseline: 1.3055x; 1.3055x over previous
//
#include <hip/hip_runtime.h>

#define N_TOK 32768
#define N_E   1024
#define E_DIM 64
#define N_BLK 1024
#define RPB2  16
#define SINK_PASSES 3

__device__ __forceinline__ unsigned fkey(float f) {
  unsigned u = __float_as_uint(f);
  return (u & 0x80000000u) ? ~u : (u | 0x80000000u);
}
__device__ __forceinline__ float fdecode(unsigned k) {
  unsigned u = (k & 0x80000000u) ? (k & 0x7FFFFFFFu) : ~k;
  return __uint_as_float(u);
}

__global__ void k0_init(unsigned* minmax, int* usage_i) {
  int t = threadIdx.x;
  if (t == 0) { minmax[0] = 0xFFFFFFFFu; minmax[1] = 0u; }
  for (int i = t; i < N_E; i += 256) usage_i[i] = 0;
}

__global__ void k1_embT(const float* __restrict__ emb, float* __restrict__ embT,
                        float* __restrict__ s_e) {
  int k = blockIdx.x * blockDim.x + threadIdx.x;
  if (k >= N_E) return;
  float s = 0.f;
  for (int j = 0; j < E_DIM; ++j) {
    float v = emb[k * E_DIM + j];
    embT[j * N_E + k] = v;
    s = fmaf(v, v, s);
  }
  s_e[k] = s;
}

// d (f32, bit-identical accumulation order to validated r6/r8) + min/max + ||x||^2.
__global__ __launch_bounds__(256) void k2_dist(const float* __restrict__ x,
    const float* __restrict__ embT, const float* __restrict__ s_e,
    float* __restrict__ dcbuf, unsigned* __restrict__ minmax,
    float* __restrict__ xnorm) {
  __shared__ float xs[RPB2][E_DIM + 4];
  __shared__ float sxl[RPB2];
  __shared__ float smn[4], smx[4];
  const int tid = threadIdx.x;
  const int r0 = blockIdx.x * RPB2;
  for (int i = tid; i < RPB2 * E_DIM; i += 256)
    xs[i >> 6][i & 63] = x[r0 * E_DIM + i];
  __syncthreads();
  if (tid < RPB2) {
    float s = 0.f;
    for (int j = 0; j < E_DIM; ++j) s = fmaf(xs[tid][j], xs[tid][j], s);
    sxl[tid] = s;
    xnorm[r0 + tid] = s;
  }
  __syncthreads();
  const int c0 = tid * 4;
  const float4 se4 = *(const float4*)(s_e + c0);
  const int w = tid >> 6, l = tid & 63;
  float dmn = INFINITY, dmx = -INFINITY;
  for (int rg = 0; rg < 2; ++rg) {
    float acc[4][8];
    #pragma unroll
    for (int a = 0; a < 4; ++a)
      #pragma unroll
      for (int b = 0; b < 8; ++b) acc[a][b] = 0.f;
    for (int j0 = 0; j0 < E_DIM; j0 += 4) {
      float4 eq[4];
      #pragma unroll
      for (int jj = 0; jj < 4; ++jj)
        eq[jj] = *(const float4*)(embT + (size_t)(j0 + jj) * N_E + c0);
      const float* ef = (const float*)eq;
      #pragma unroll
      for (int b = 0; b < 8; ++b) {
        const float4 xv = *(const float4*)(&xs[rg * 8 + b][j0]);
        #pragma unroll
        for (int a = 0; a < 4; ++a) {
          acc[a][b] = fmaf(ef[0 * 4 + a], xv.x, acc[a][b]);
          acc[a][b] = fmaf(ef[1 * 4 + a], xv.y, acc[a][b]);
          acc[a][b] = fmaf(ef[2 * 4 + a], xv.z, acc[a][b]);
          acc[a][b] = fmaf(ef[3 * 4 + a], xv.w, acc[a][b]);
        }
      }
    }
    #pragma unroll
    for (int b = 0; b < 8; ++b) {
      const int row = r0 + rg * 8 + b;
      const float t = sxl[rg * 8 + b];
      float4 dv;
      dv.x = (t + se4.x) - 2.0f * acc[0][b];
      dv.y = (t + se4.y) - 2.0f * acc[1][b];
      dv.z = (t + se4.z) - 2.0f * acc[2][b];
      dv.w = (t + se4.w) - 2.0f * acc[3][b];
      *(float4*)(dcbuf + (size_t)row * N_E + c0) = dv;
      dmn = fminf(dmn, fminf(fminf(dv.x, dv.y), fminf(dv.z, dv.w)));
      dmx = fmaxf(dmx, fmaxf(fmaxf(dv.x, dv.y), fmaxf(dv.z, dv.w)));
    }
  }
  for (int off = 32; off; off >>= 1) {
    dmn = fminf(dmn, __shfl_xor(dmn, off));
    dmx = fmaxf(dmx, __shfl_xor(dmx, off));
  }
  if (l == 0) { smn[w] = dmn; smx[w] = dmx; }
  __syncthreads();
  if (tid == 0) {
    float a = fminf(fminf(smn[0], smn[1]), fminf(smn[2], smn[3]));
    float b = fmaxf(fmaxf(smx[0], smx[1]), fmaxf(smx[2], smx[3]));
    atomicMin(&minmax[0], fkey(a));
    atomicMax(&minmax[1], fkey(b));
  }
}

// One Sinkhorn iteration (validated r8 single-sweep form).
__global__ __launch_bounds__(256) void k4_pass(const float* __restrict__ dcbuf,
    const float* __restrict__ xnorm, const unsigned* __restrict__ minmax,
    const double* __restrict__ u_in, double* __restrict__ Up, int phase) {
  __shared__ double ulds[4][N_E];
  const float mn = fdecode(minmax[0]);
  const float mx = fdecode(minmax[1]);
  const float middle = (mx + mn) * 0.5f;
  const float amplitude = (mx - middle) + 1e-5f;
  const float s2 = 144.26950408889634f / amplitude;   // 100*log2(e)/amp
  const double escale = -100.0 / (double)amplitude;
  const double mid_d = (double)middle;
  const int tid = threadIdx.x, w = tid >> 6, l = tid & 63;
  const int bid = blockIdx.x;
  const int r0 = bid * 32;
  double rr[16];
  if (phase) {
    #pragma unroll
    for (int q = 0; q < 4; ++q)
      #pragma unroll
      for (int m = 0; m < 4; ++m)
        rr[q * 4 + m] = 1.0 / (1024.0 * u_in[4 * l + 256 * q + m]);
  }
  double ua[16];
  #pragma unroll
  for (int j = 0; j < 16; ++j) ua[j] = 0.0;
  for (int i = 0; i < 8; ++i) {
    const int row = r0 + w + 4 * i;
    const float* dr = dcbuf + (size_t)row * N_E;
    const float m2 = xnorm[row];
    float E[16];
    #pragma unroll
    for (int q = 0; q < 4; ++q) {
      const float4 v = *(const float4*)(dr + 4 * l + 256 * q);
      E[q * 4 + 0] = exp2f((m2 - v.x) * s2);
      E[q * 4 + 1] = exp2f((m2 - v.y) * s2);
      E[q * 4 + 2] = exp2f((m2 - v.z) * s2);
      E[q * 4 + 3] = exp2f((m2 - v.w) * s2);
    }
    double ch;
    if (phase) {
      double vs = 0.0;
      #pragma unroll
      for (int j = 0; j < 16; ++j) vs = fma((double)E[j], rr[j], vs);
      for (int off = 32; off; off >>= 1) vs += __shfl_xor(vs, off);
      ch = 1.0 / (32768.0 * vs);
    } else {
      ch = exp(escale * ((double)m2 - mid_d));
    }
    #pragma unroll
    for (int j = 0; j < 16; ++j) ua[j] = fma((double)E[j], ch, ua[j]);
  }
  #pragma unroll
  for (int q = 0; q < 4; ++q)
    #pragma unroll
    for (int m = 0; m < 4; ++m)
      ulds[w][4 * l + 256 * q + m] = ua[q * 4 + m];
  __syncthreads();
  #pragma unroll
  for (int k = 0; k < 4; ++k) {
    const int c = tid * 4 + k;
    const double s = ulds[0][c] + ulds[1][c] + ulds[2][c] + ulds[3][c];
    Up[(size_t)c * N_BLK + bid] = s;
  }
}

__global__ __launch_bounds__(256) void k4_reduce(const double* __restrict__ Up,
                                                 double* __restrict__ u,
                                                 double* __restrict__ logu, int last) {
  __shared__ double red[4];
  const int c = blockIdx.x;
  const int tid = threadIdx.x, w = tid >> 6, l = tid & 63;
  double s = 0.0;
  for (int i = tid; i < N_BLK; i += 256) s += Up[(size_t)c * N_BLK + i];
  for (int off = 32; off; off >>= 1) s += __shfl_xor(s, off);
  if (l == 0) red[w] = s;
  __syncthreads();
  if (tid == 0) {
    const double t = red[0] + red[1] + red[2] + red[3];
    u[c] = t;
    if (last) logu[c] = -log(t);
  }
}

__global__ __launch_bounds__(256) void k5_out(const float* __restrict__ dcbuf,
    const double* __restrict__ logu, const unsigned* __restrict__ minmax,
    const float* __restrict__ x, const float* __restrict__ emb,
    float* __restrict__ out_xq, float* __restrict__ out_idx,
    int* __restrict__ usage_i, double* __restrict__ lossP) {
  __shared__ double slr[N_E];
  __shared__ double lw[4];
  const float mn = fdecode(minmax[0]);
  const float mx = fdecode(minmax[1]);
  const float middle = (mx + mn) * 0.5f;
  const float amplitude = (mx - middle) + 1e-5f;
  const int tid = threadIdx.x, w = tid >> 6, l = tid & 63;
  const int r0 = blockIdx.x * 32;
  for (int t = tid; t < N_E; t += 256) slr[t] = logu[t];
  __syncthreads();
  double lacc = 0.0;
  for (int i = 0; i < 8; ++i) {
    const int row = r0 + w * 8 + i;
    const float* dr = dcbuf + (size_t)row * N_E;
    double best = -INFINITY; int bc = 0;
    #pragma unroll
    for (int m = 0; m < 16; ++m) {
      const int c = l + 64 * m;
      const float v = (dr[c] - middle) / amplitude;   // reference f32 rounding
      const double s = slr[c] - (double)v * 100.0;
      if (s > best) { best = s; bc = c; }
    }
    for (int off = 32; off; off >>= 1) {
      const double ob = __shfl_xor(best, off);
      const int oc = __shfl_xor(bc, off);
      if (ob > best || (ob == best && oc < bc)) { best = ob; bc = oc; }
    }
    if (l == 0) {
      out_idx[row] = (float)bc;
      atomicAdd(&usage_i[bc], 1);
    }
    const float g = emb[bc * E_DIM + l];
    const float xv = x[(size_t)row * E_DIM + l];
    const float diff = g - xv;
    out_xq[(size_t)row * E_DIM + l] = xv + diff;
    lacc += (double)diff * (double)diff;
  }
  for (int off = 32; off; off >>= 1) lacc += __shfl_xor(lacc, off);
  if (l == 0) lw[w] = lacc;
  __syncthreads();
  if (tid == 0) lossP[blockIdx.x] = lw[0] + lw[1] + lw[2] + lw[3];
}

__global__ void k6_final(const int* __restrict__ usage_in,
    const int* __restrict__ usage_i, const double* __restrict__ lossP,
    float* __restrict__ out_loss, float* __restrict__ out_usage) {
  __shared__ double red[4];
  const int tid = threadIdx.x;
  if (blockIdx.x < 4) {
    const int t = blockIdx.x * 256 + tid;
    out_usage[t] = (float)(usage_in[t] + usage_i[t]);
  } else {
    const int w = tid >> 6, l = tid & 63;
    double s = 0.0;
    for (int i = tid; i < N_BLK; i += 256) s += lossP[i];
    for (int off = 32; off; off >>= 1) s += __shfl_xor(s, off);
    if (l == 0) red[w] = s;
    __syncthreads();
    if (tid == 0)
      out_loss[0] = (float)(2.0 * (red[0] + red[1] + red[2] + red[3]) /
                            (double)((size_t)N_TOK * E_DIM));
  }
}

extern "C" void kernel_launch(void* const* d_in, const int* in_sizes, int n_in,
                              void* d_out, int out_size, void* d_ws, size_t ws_size,
                              hipStream_t stream) {
  const float* x = (const float*)d_in[0];
  const float* emb = (const float*)d_in[1];
  const int* usage_in = (const int*)d_in[4];   // harness: integer inputs are int32
  float* out = (float*)d_out;
  float* out_xq = out;
  float* out_loss = out + (size_t)N_TOK * E_DIM;
  float* out_idx = out_loss + 1;
  float* out_usage = out_idx + N_TOK;

  char* ws = (char*)d_ws;
  size_t off = 0;
  float* dcbuf     = (float*)(ws + off); off += (size_t)N_TOK * N_E * 4;
  float* embT      = (float*)(ws + off); off += (size_t)E_DIM * N_E * 4;
  float* s_e       = (float*)(ws + off); off += N_E * 4;
  float* xnorm     = (float*)(ws + off); off += N_TOK * 4;
  double* ubuf     = (double*)(ws + off); off += N_E * 8;
  double* logu     = (double*)(ws + off); off += N_E * 8;
  double* Up       = (double*)(ws + off); off += (size_t)N_E * N_BLK * 8;
  double* lossP    = (double*)(ws + off); off += N_BLK * 8;
  unsigned* minmax = (unsigned*)(ws + off); off += 8;
  int* usage_i     = (int*)(ws + off); off += N_E * 4;

  hipLaunchKernelGGL(k0_init, dim3(1), dim3(256), 0, stream, minmax, usage_i);
  hipLaunchKernelGGL(k1_embT, dim3(4), dim3(256), 0, stream, emb, embT, s_e);
  hipLaunchKernelGGL(k2_dist, dim3(N_TOK / RPB2), dim3(256), 0, stream, x, embT, s_e,
                     dcbuf, minmax, xnorm);
  for (int p = 0; p < SINK_PASSES; ++p) {
    hipLaunchKernelGGL(k4_pass, dim3(N_BLK), dim3(256), 0, stream, dcbuf, xnorm,
                       minmax, ubuf, Up, p);
    hipLaunchKernelGGL(k4_reduce, dim3(N_E), dim3(256), 0, stream, Up, ubuf, logu,
                       (p == SINK_PASSES - 1) ? 1 : 0);
  }
  hipLaunchKernelGGL(k5_out, dim3(N_BLK), dim3(256), 0, stream, dcbuf, logu, minmax,
                     x, emb, out_xq, out_idx, usage_i, lossP);
  hipLaunchKernelGGL(k6_final, dim3(5), dim3(256), 0, stream, usage_in, usage_i,
                     lossP, out_loss, out_usage);
}